// Round 1
// baseline (119.930 us; speedup 1.0000x reference)
//
#include <hip/hip_runtime.h>

// OESNN_SEPhIA_MultiTiled2: 32-step recurrent SNN, B=8192.
// Decomposition: 4 lanes per batch element (tile x half of the 18 layer-0
// channels); layer-1 exchange via __shfl (no LDS/barriers). Weights live in
// registers (launch_bounds(64,1) -> 512-VGPR budget; only 512 waves exist).
// Numerics mimic the reference order exactly (ascending-w fma chains,
// separate even/odd sums, select-based LIF reset) to avoid spike flips.

namespace {
constexpr int Tn = 32;
constexpr int Bn = 8192;
constexpr int O_PW = 0;                       // spks0 (= pw0) [T,B,18]
constexpr int O_S1 = Tn * Bn * 18;            // spks1 [T,B,8]
constexpr int O_M0 = O_S1 + Tn * Bn * 8;      // mems0 [T,B,18]
constexpr int O_M1 = O_M0 + Tn * Bn * 18;     // mems1 [T,B,8]
}

__global__ __launch_bounds__(64, 1)
void oesnn_kernel(const float* __restrict__ x_in,
                  const float* __restrict__ W0g,   // [2,18,18]
                  const float* __restrict__ d0g,   // [2,9]
                  const float* __restrict__ W1g,   // [1,18,16]
                  const float* __restrict__ d1g,   // [1,8]
                  const float* __restrict__ peakg, // [36]
                  float* __restrict__ out)
{
    const int lt  = threadIdx.x;              // 0..63
    const int tid = blockIdx.x * 64 + lt;
    const int b   = tid >> 2;                 // batch element
    const int sub = tid & 3;                  // lane within batch group
    const int tl  = sub & 1;                  // layer-0 tile (0/1)
    const int h   = sub >> 1;                 // half within tile
    const int j0  = h ? 5 : 0;                // first in-tile channel
    const int nj  = h ? 4 : 5;                // real channel count (dup pads to 5)

    // ---------------- per-lane weight preload into registers ----------------
    float w0e[5][18], w0o[5][18], dd0[5], pon[5], poff[5];
    #pragma unroll
    for (int j = 0; j < 5; ++j) {
        const int jc = (j < nj) ? (j0 + j) : j0;   // clamped (dup stays in-lane)
        dd0[j] = d0g[tl * 9 + jc];
        #pragma unroll
        for (int w = 0; w < 18; ++w) {
            const float2 p = *(const float2*)(W0g + ((tl * 18 + w) * 18 + 2 * jc));
            w0e[j][w] = p.x;
            w0o[j][w] = p.y;
        }
        // pw0 takes exactly two values per channel: precompute via the
        // reference's complex-division -> abs -> square path.
        const int c = tl * 9 + jc;
        const float wl    = 1550.0f + 0.8f * (float)c;
        const float halfw = 0.5f * (wl * 1e3f / 15000.0f);
        const float amp   = sqrtf((exp10f(peakg[c] / 10.0f) / 1000.0f) * 1e6f);
        {   // spike = 0: lo = (0.1 + 0i)/(1 + 0i) * amp
            const float lr = 0.1f * amp;
            const float a  = sqrtf(lr * lr);
            poff[j] = a * a;
        }
        {   // spike = 1: delta = -250 / (0.5*fwhm)
            const float delta = -250.0f / halfw;
            const float den = fmaf(delta, delta, 1.0f);
            const float qr  = fmaf(delta, delta, 0.1f) / den;     // (g + d^2)/den
            const float qi  = (delta - 0.1f * delta) / den;       // (d - g*d)/den
            const float lr = qr * amp, li = qi * amp;
            const float a  = sqrtf(fmaf(lr, lr, li * li));
            pon[j] = a * a;
        }
    }

    // layer-1: this lane owns output channels jj = {2*sub, 2*sub+1},
    // i.e. columns s = 4*sub .. 4*sub+3 of W1.
    float w1v[4][18], dd1[2];
    #pragma unroll
    for (int k = 0; k < 4; ++k) {
        const int s = 4 * sub + k;
        #pragma unroll
        for (int w = 0; w < 18; ++w)
            w1v[k][w] = W1g[w * 16 + s];
    }
    dd1[0] = d1g[2 * sub];
    dd1[1] = d1g[2 * sub + 1];

    // ---------------- state & pointers ----------------
    float mem0[5] = {0.f, 0.f, 0.f, 0.f, 0.f};
    float mem1[2] = {0.f, 0.f};

    const float* xp = x_in + (size_t)b * 36 + tl * 18;
    float* opw = out + O_PW + (size_t)b * 18 + tl * 9 + j0;
    float* om0 = out + O_M0 + (size_t)b * 18 + tl * 9 + j0;
    float* os1 = out + O_S1 + (size_t)b * 8 + 2 * sub;
    float* om1 = out + O_M1 + (size_t)b * 8 + 2 * sub;

    // prefetch t=0 inputs (18 floats = 9x float2, 8B-aligned)
    float2 xv[9];
    #pragma unroll
    for (int k = 0; k < 9; ++k) xv[k] = *(const float2*)(xp + 2 * k);

    #pragma unroll 1
    for (int t = 0; t < Tn; ++t) {
        // unpack current x, scale to optical power (reference: p_in = x * 1e-4)
        float p[18];
        #pragma unroll
        for (int k = 0; k < 9; ++k) {
            p[2 * k]     = xv[k].x * 1e-4f;
            p[2 * k + 1] = xv[k].y * 1e-4f;
        }
        // prefetch next timestep while computing this one
        xp += Bn * 36;
        if (t < Tn - 1) {
            #pragma unroll
            for (int k = 0; k < 9; ++k) xv[k] = *(const float2*)(xp + 2 * k);
        }

        // ---- layer 0: I0 even/odd columns, balanced PD, LIF, MRR power ----
        float pwv[5];
        #pragma unroll
        for (int j = 0; j < 5; ++j) {
            float se = 0.f, so = 0.f;
            #pragma unroll
            for (int w = 0; w < 18; ++w) {
                se = fmaf(p[w], w0e[j][w], se);
                so = fmaf(p[w], w0o[j][w], so);
            }
            const float c0 = (se - so) * dd0[j];
            const float m  = mem0[j];
            const float m2 = (m > 0.55f) ? 0.0f : fmaf(0.95f, m, c0);
            mem0[j] = m2;
            pwv[j]  = (m2 > 0.55f) ? pon[j] : poff[j];
        }

        // store pw0 / mem0 (guard the dup channel on 4-channel lanes)
        #pragma unroll
        for (int j = 0; j < 5; ++j) {
            if (j < nj) {
                opw[j] = pwv[j];
                om0[j] = mem0[j];
            }
        }

        // ---- cross-lane gather of all 18 pw values (exact ascending order) ----
        const int basel = lt & ~3;
        float pwall[18];
        #pragma unroll
        for (int c = 0; c < 18; ++c) {
            const int tlc = c / 9, jc2 = c % 9;
            const int hc  = (jc2 >= 5) ? 1 : 0;
            const int src = (hc << 1) | tlc;           // owner sub-lane
            pwall[c] = __shfl(pwv[jc2 - 5 * hc], basel + src, 64);
        }

        // ---- layer 1: ascending-w fma into this lane's 4 columns ----
        float I1[4] = {0.f, 0.f, 0.f, 0.f};
        #pragma unroll
        for (int w = 0; w < 18; ++w) {
            #pragma unroll
            for (int k = 0; k < 4; ++k)
                I1[k] = fmaf(pwall[w], w1v[k][w], I1[k]);
        }

        float2 s1o, m1o;
        {
            const float c1 = (I1[0] - I1[1]) * dd1[0];
            const float m  = mem1[0];
            const float m2 = (m > 0.25f) ? 0.0f : fmaf(0.95f, m, c1);
            mem1[0] = m2;
            s1o.x = (m2 > 0.25f) ? 1.0f : 0.0f;
            m1o.x = m2;
        }
        {
            const float c1 = (I1[2] - I1[3]) * dd1[1];
            const float m  = mem1[1];
            const float m2 = (m > 0.25f) ? 0.0f : fmaf(0.95f, m, c1);
            mem1[1] = m2;
            s1o.y = (m2 > 0.25f) ? 1.0f : 0.0f;
            m1o.y = m2;
        }
        *(float2*)os1 = s1o;
        *(float2*)om1 = m1o;

        opw += Bn * 18;
        om0 += Bn * 18;
        os1 += Bn * 8;
        om1 += Bn * 8;
    }
}

extern "C" void kernel_launch(void* const* d_in, const int* in_sizes, int n_in,
                              void* d_out, int out_size, void* d_ws, size_t ws_size,
                              hipStream_t stream) {
    (void)in_sizes; (void)n_in; (void)out_size; (void)d_ws; (void)ws_size;
    const float* x  = (const float*)d_in[0];
    const float* W0 = (const float*)d_in[1];
    const float* d0 = (const float*)d_in[2];
    const float* W1 = (const float*)d_in[3];
    const float* d1 = (const float*)d_in[4];
    const float* pk = (const float*)d_in[5];
    float* out = (float*)d_out;

    dim3 grid(Bn * 4 / 64), block(64);
    hipLaunchKernelGGL(oesnn_kernel, grid, block, 0, stream,
                       x, W0, d0, W1, d1, pk, out);
}

// Round 2
// 117.125 us; speedup vs baseline: 1.0239x; 1.0239x over previous
//
#include <hip/hip_runtime.h>

// OESNN_SEPhIA_MultiTiled2: 32-step recurrent SNN, B=8192.
// R2: 8 lanes per batch element (was 4). Each lane owns <=3 layer-0 channels
// (36 weight regs each) and exactly 1 layer-1 output (36 weight regs), so the
// full weight set fits the 256-VGPR architectural file -> no spill/remat in
// the t-loop. 1024 waves = 1 wave/SIMD chip-wide. Cross-lane exchange of the
// 18 pw values via __shfl within 8-lane groups (no LDS, no barriers).
// Numerics are op-for-op identical to the R1 passing kernel (ascending-w
// single-accumulator fma chains, separate even/odd sums, select-based LIF).

namespace {
constexpr int Tn = 32;
constexpr int Bn = 8192;
constexpr int O_PW = 0;                       // spks0 (= pw0) [T,B,18]
constexpr int O_S1 = Tn * Bn * 18;            // spks1 [T,B,8]
constexpr int O_M0 = O_S1 + Tn * Bn * 8;      // mems0 [T,B,18]
constexpr int O_M1 = O_M0 + Tn * Bn * 18;     // mems1 [T,B,8]
}

__global__ __launch_bounds__(256, 1)
void oesnn_kernel(const float* __restrict__ x_in,
                  const float* __restrict__ W0g,   // [2,18,18]
                  const float* __restrict__ d0g,   // [2,9]
                  const float* __restrict__ W1g,   // [1,18,16]
                  const float* __restrict__ d1g,   // [1,8]
                  const float* __restrict__ peakg, // [36]
                  float* __restrict__ out)
{
    const int lt  = threadIdx.x & 63;         // lane in wave
    const int tid = blockIdx.x * 256 + threadIdx.x;
    const int b   = tid >> 3;                 // batch element
    const int sub = tid & 7;                  // lane within batch group
    const int tl  = sub >> 2;                 // layer-0 tile (0/1)
    const int q   = sub & 3;                  // lane within tile
    const int j0  = (q == 0) ? 0 : (2 * q + 1);   // first in-tile channel
    const int nj  = (q == 0) ? 3 : 2;             // real channel count (pad to 3)

    // ---------------- per-lane weight preload into registers ----------------
    float w0e[3][18], w0o[3][18], dd0[3], pon[3], poff[3];
    #pragma unroll
    for (int j = 0; j < 3; ++j) {
        const int jc = (j < nj) ? (j0 + j) : j0;   // clamped dup stays in-lane
        dd0[j] = d0g[tl * 9 + jc];
        #pragma unroll
        for (int w = 0; w < 18; ++w) {
            const float2 p = *(const float2*)(W0g + ((tl * 18 + w) * 18 + 2 * jc));
            w0e[j][w] = p.x;
            w0o[j][w] = p.y;
        }
        // pw0 takes exactly two values per channel: precompute via the
        // reference's complex-division -> abs -> square path.
        const int c = tl * 9 + jc;
        const float wl    = 1550.0f + 0.8f * (float)c;
        const float halfw = 0.5f * (wl * 1e3f / 15000.0f);
        const float amp   = sqrtf((exp10f(peakg[c] / 10.0f) / 1000.0f) * 1e6f);
        {   // spike = 0: lo = (0.1 + 0i)/(1 + 0i) * amp
            const float lr = 0.1f * amp;
            const float a  = sqrtf(lr * lr);
            poff[j] = a * a;
        }
        {   // spike = 1: delta = -250 / (0.5*fwhm)
            const float delta = -250.0f / halfw;
            const float den = fmaf(delta, delta, 1.0f);
            const float qr  = fmaf(delta, delta, 0.1f) / den;     // (g + d^2)/den
            const float qi  = (delta - 0.1f * delta) / den;       // (d - g*d)/den
            const float lr = qr * amp, li = qi * amp;
            const float a  = sqrtf(fmaf(lr, lr, li * li));
            pon[j] = a * a;
        }
    }

    // layer-1: lane `sub` owns output channel o = sub (columns 2o, 2o+1).
    float w1e[18], w1o[18];
    #pragma unroll
    for (int w = 0; w < 18; ++w) {
        const float2 pp = *(const float2*)(W1g + w * 16 + 2 * sub);  // 8B-aligned
        w1e[w] = pp.x;
        w1o[w] = pp.y;
    }
    const float dd1 = d1g[sub];

    // ---------------- state & pointers ----------------
    float mem0[3] = {0.f, 0.f, 0.f};
    float mem1 = 0.f;

    const float* xp = x_in + (size_t)b * 36 + tl * 18;
    float* opw = out + O_PW + (size_t)b * 18 + tl * 9 + j0;
    float* om0 = out + O_M0 + (size_t)b * 18 + tl * 9 + j0;
    float* os1 = out + O_S1 + (size_t)b * 8 + sub;
    float* om1 = out + O_M1 + (size_t)b * 8 + sub;

    // prefetch t=0 inputs (18 floats = 9x float2, 8B-aligned)
    float2 xv[9];
    #pragma unroll
    for (int k = 0; k < 9; ++k) xv[k] = *(const float2*)(xp + 2 * k);

    const int basel = lt & ~7;

    #pragma unroll 1
    for (int t = 0; t < Tn; ++t) {
        // unpack current x, scale to optical power (reference: p_in = x * 1e-4)
        float p[18];
        #pragma unroll
        for (int k = 0; k < 9; ++k) {
            p[2 * k]     = xv[k].x * 1e-4f;
            p[2 * k + 1] = xv[k].y * 1e-4f;
        }
        // prefetch next timestep while computing this one
        xp += Bn * 36;
        if (t < Tn - 1) {
            #pragma unroll
            for (int k = 0; k < 9; ++k) xv[k] = *(const float2*)(xp + 2 * k);
        }

        // ---- layer 0: I0 even/odd columns, balanced PD, LIF, MRR power ----
        float pwv[3];
        #pragma unroll
        for (int j = 0; j < 3; ++j) {
            float se = 0.f, so = 0.f;
            #pragma unroll
            for (int w = 0; w < 18; ++w) {
                se = fmaf(p[w], w0e[j][w], se);
                so = fmaf(p[w], w0o[j][w], so);
            }
            const float c0 = (se - so) * dd0[j];
            const float m  = mem0[j];
            const float m2 = (m > 0.55f) ? 0.0f : fmaf(0.95f, m, c0);
            mem0[j] = m2;
            pwv[j]  = (m2 > 0.55f) ? pon[j] : poff[j];
        }

        // store pw0 / mem0 (guard the dup channel on 2-channel lanes)
        #pragma unroll
        for (int j = 0; j < 3; ++j) {
            if (j < nj) {
                opw[j] = pwv[j];
                om0[j] = mem0[j];
            }
        }

        // ---- cross-lane gather of all 18 pw values ----
        float pwall[18];
        #pragma unroll
        for (int c = 0; c < 18; ++c) {
            const int tlc = c / 9, jc2 = c % 9;
            const int qo  = (jc2 < 3) ? 0 : ((jc2 - 1) / 2);   // owner lane-in-tile
            const int st  = (qo == 0) ? 0 : (2 * qo + 1);
            const int r   = jc2 - st;                          // owner's reg index
            pwall[c] = __shfl(pwv[r], basel + tlc * 4 + qo, 64);
        }

        // ---- layer 1: ascending-w fma into this lane's 2 columns ----
        float i1e = 0.f, i1o = 0.f;
        #pragma unroll
        for (int w = 0; w < 18; ++w) {
            i1e = fmaf(pwall[w], w1e[w], i1e);
            i1o = fmaf(pwall[w], w1o[w], i1o);
        }

        const float c1 = (i1e - i1o) * dd1;
        const float m  = mem1;
        const float m2 = (m > 0.25f) ? 0.0f : fmaf(0.95f, m, c1);
        mem1 = m2;
        *os1 = (m2 > 0.25f) ? 1.0f : 0.0f;   // 64 lanes -> 64 consecutive dwords
        *om1 = m2;

        opw += Bn * 18;
        om0 += Bn * 18;
        os1 += Bn * 8;
        om1 += Bn * 8;
    }
}

extern "C" void kernel_launch(void* const* d_in, const int* in_sizes, int n_in,
                              void* d_out, int out_size, void* d_ws, size_t ws_size,
                              hipStream_t stream) {
    (void)in_sizes; (void)n_in; (void)out_size; (void)d_ws; (void)ws_size;
    const float* x  = (const float*)d_in[0];
    const float* W0 = (const float*)d_in[1];
    const float* d0 = (const float*)d_in[2];
    const float* W1 = (const float*)d_in[3];
    const float* d1 = (const float*)d_in[4];
    const float* pk = (const float*)d_in[5];
    float* out = (float*)d_out;

    dim3 grid(Bn * 8 / 256), block(256);
    hipLaunchKernelGGL(oesnn_kernel, grid, block, 0, stream,
                       x, W0, d0, W1, d1, pk, out);
}